// Round 6
// baseline (564.666 us; speedup 1.0000x reference)
//
#include <hip/hip_runtime.h>

// CRF NLL forward loss. B=256, T=2048, K2=52 (50 labels + START=50 + STOP=51).
// Linear-domain forward recurrence, one wave per batch, no LDS, no barriers.
//   v_{t+1}[n] = E_t[n] * (sum_p M2[n][p] v_t[p]),  renorm by v[50] every 4 steps.
// R5 lesson: PIN outside the loop let the allocator move M to AGPRs for the
// loop body (VGPR_Count=40!), adding v_accvgpr_read per use; and the
// readlane->fma distance-1 pattern added VALU->SGPR->VALU wait states.
// Fix: PIN *inside* the loop (forces arch-VGPR residence across back-edge) and
// group 13 readlanes -> 13 fmas so SGPR consumers are 13 instructions away.

#define B_    256
#define T_    2048
#define K2_   52
#define LOG2E_ 1.4426950408889634f
#define LN2_   0.6931471805599453f

__device__ __forceinline__ float rdlane(float v, int src) {
  return __uint_as_float(__builtin_amdgcn_readlane(__float_as_uint(v), src));
}

#define FORALL52(F) \
  F(0) F(1) F(2) F(3) F(4) F(5) F(6) F(7) F(8) F(9) F(10) F(11) F(12) \
  F(13) F(14) F(15) F(16) F(17) F(18) F(19) F(20) F(21) F(22) F(23) F(24) F(25) \
  F(26) F(27) F(28) F(29) F(30) F(31) F(32) F(33) F(34) F(35) F(36) F(37) F(38) \
  F(39) F(40) F(41) F(42) F(43) F(44) F(45) F(46) F(47) F(48) F(49) F(50) F(51)

#define DECLM(i) float M_##i = __builtin_amdgcn_exp2f(tr[n * K2_ + i] * LOG2E_);

// 13 uniform readlanes (SGPR temps), then 13 fmas (consumers >=13 instrs away).
#define GROUP13(i0,i1,i2,i3,i4,i5,i6,i7,i8,i9,i10,i11,i12) do {      \
    float t0  = rdlane(vv, i0),  t1  = rdlane(vv, i1);               \
    float t2  = rdlane(vv, i2),  t3  = rdlane(vv, i3);               \
    float t4  = rdlane(vv, i4),  t5  = rdlane(vv, i5);               \
    float t6  = rdlane(vv, i6),  t7  = rdlane(vv, i7);               \
    float t8  = rdlane(vv, i8),  t9  = rdlane(vv, i9);               \
    float t10 = rdlane(vv, i10), t11 = rdlane(vv, i11);              \
    float t12 = rdlane(vv, i12);                                     \
    _a0 = fmaf(M_##i0,  t0,  _a0);  _a1 = fmaf(M_##i1,  t1,  _a1);   \
    _a2 = fmaf(M_##i2,  t2,  _a2);  _a3 = fmaf(M_##i3,  t3,  _a3);   \
    _a0 = fmaf(M_##i4,  t4,  _a0);  _a1 = fmaf(M_##i5,  t5,  _a1);   \
    _a2 = fmaf(M_##i6,  t6,  _a2);  _a3 = fmaf(M_##i7,  t7,  _a3);   \
    _a0 = fmaf(M_##i8,  t8,  _a0);  _a1 = fmaf(M_##i9,  t9,  _a1);   \
    _a2 = fmaf(M_##i10, t10, _a2);  _a3 = fmaf(M_##i11, t11, _a3);   \
    _a0 = fmaf(M_##i12, t12, _a0);                                   \
  } while (0)

#define MATVEC(OUTY) \
    float _a0 = 0.0f, _a1 = 0.0f, _a2 = 0.0f, _a3 = 0.0f;            \
    GROUP13( 0, 1, 2, 3, 4, 5, 6, 7, 8, 9,10,11,12);                 \
    GROUP13(13,14,15,16,17,18,19,20,21,22,23,24,25);                 \
    GROUP13(26,27,28,29,30,31,32,33,34,35,36,37,38);                 \
    GROUP13(39,40,41,42,43,44,45,46,47,48,49,50,51);                 \
    float OUTY = (_a0 + _a1) + (_a2 + _a3);

// Step WITH single-lane renorm (lane 50 = START, always > 0 after step 0).
#define STEP_R(EV, NEWIDX) do {                                 \
    float _ne  = emb[(NEWIDX) * K2_ + n];                       \
    float _m   = rdlane(vv, 50);                                \
    float _inv = __builtin_amdgcn_rcpf(_m);                     \
    C += __builtin_amdgcn_logf(_m);        /* v_log_f32 = log2 */ \
    float _E = __builtin_amdgcn_exp2f((EV) * LOG2E_);           \
    MATVEC(_y)                                                  \
    vv = _y * _inv * _E;                                        \
    EV = _ne;                                                   \
  } while (0)

// Step WITHOUT renorm (growth over <=4 unnormalized steps stays in fp32 range).
#define STEP_N(EV, NEWIDX) do {                                 \
    float _ne  = emb[(NEWIDX) * K2_ + n];                       \
    float _E = __builtin_amdgcn_exp2f((EV) * LOG2E_);           \
    MATVEC(_y)                                                  \
    vv = _y * _E;                                               \
    EV = _ne;                                                   \
  } while (0)

#define PIN(a,b,c,d,e,f,g,h,i,j,k,l,m) \
  asm volatile("" : "+v"(M_##a), "+v"(M_##b), "+v"(M_##c), "+v"(M_##d), \
                    "+v"(M_##e), "+v"(M_##f), "+v"(M_##g), "+v"(M_##h), \
                    "+v"(M_##i), "+v"(M_##j), "+v"(M_##k), "+v"(M_##l), \
                    "+v"(M_##m));

#define PIN_ALL \
  PIN( 0, 1, 2, 3, 4, 5, 6, 7, 8, 9,10,11,12) \
  PIN(13,14,15,16,17,18,19,20,21,22,23,24,25) \
  PIN(26,27,28,29,30,31,32,33,34,35,36,37,38) \
  PIN(39,40,41,42,43,44,45,46,47,48,49,50,51)

__launch_bounds__(64, 1)
__attribute__((amdgpu_waves_per_eu(1, 1)))
__global__ void crf_fwd_kernel(const float* __restrict__ em,
                               const float* __restrict__ tr,
                               const int*  __restrict__ len,
                               const int*  __restrict__ lab,
                               float* __restrict__ per_b)
{
  const int b    = blockIdx.x;
  const int lane = threadIdx.x;                      // 64
  const int n    = (lane < K2_) ? lane : (K2_ - 1);  // lanes 52..63 mirror lane 51
  const int L    = len[b];
  const float* emb = em + (size_t)b * (T_ * K2_);

  // Row n of exp2-transitions: 52 named scalars in arch VGPRs.
  FORALL52(DECLM)

  // linear-domain state; alpha = vv * 2^C.  vv starts as delta at START.
  float vv = (lane == 50) ? 1.0f : 0.0f;
  float C  = 0.0f;

  // emission prefetch ring: 4 named scalars, rotated by 4x-unrolled t-loop.
  float e0 = emb[0 * K2_ + n];
  float e1 = emb[1 * K2_ + n];
  float e2 = emb[2 * K2_ + n];
  float e3 = emb[3 * K2_ + n];

  int t = 0;
  for (; t + 4 <= L; t += 4) {
    PIN_ALL   // in-loop: M must be in arch VGPRs every iteration -> stays resident
    int i4 = t + 4, i5 = t + 5, i6 = t + 6, i7 = t + 7;
    if (i4 > T_ - 1) i4 = T_ - 1;
    if (i5 > T_ - 1) i5 = T_ - 1;
    if (i6 > T_ - 1) i6 = T_ - 1;
    if (i7 > T_ - 1) i7 = T_ - 1;
    STEP_R(e0, i4);
    STEP_N(e1, i5);
    STEP_N(e2, i6);
    STEP_N(e3, i7);
  }
  int rem = L - t;                                   // 0..3
  if (rem > 0) STEP_R(e0, T_ - 1);
  if (rem > 1) STEP_N(e1, T_ - 1);
  if (rem > 2) STEP_N(e2, T_ - 1);

  // terminal: fwd = ln2 * (C + log2 sum_p vv_p * 2^(tr2[STOP][p]))
  float stopv = (lane < K2_)
      ? vv * __builtin_amdgcn_exp2f(tr[(K2_ - 1) * K2_ + n] * LOG2E_)
      : 0.0f;
#pragma unroll
  for (int off = 32; off >= 1; off >>= 1)
    stopv += __shfl_xor(stopv, off, 64);
  float fwd = (C + __builtin_amdgcn_logf(stopv)) * LN2_;

  // gold score (raw log domain)
  float gold = 0.0f;
  const int* labb = lab + b * T_;
  for (int tt = lane; tt < L; tt += 64) {
    int l1 = labb[tt];
    int l0 = (tt == 0) ? 50 : labb[tt - 1];
    gold += emb[tt * K2_ + l1] + tr[l1 * K2_ + l0];
  }
  if (lane == 0) gold += tr[(K2_ - 1) * K2_ + labb[L - 1]];  // STOP <- last label
#pragma unroll
  for (int off = 32; off >= 1; off >>= 1)
    gold += __shfl_xor(gold, off, 64);

  if (lane == 0) per_b[b] = fwd - gold;
}

__global__ void reduce_mean_kernel(const float* __restrict__ per_b,
                                   float* __restrict__ out)
{
  const int tid = threadIdx.x;  // 256
  float v = per_b[tid];
#pragma unroll
  for (int off = 32; off >= 1; off >>= 1) v += __shfl_xor(v, off, 64);
  __shared__ float s[4];
  if ((tid & 63) == 0) s[tid >> 6] = v;
  __syncthreads();
  if (tid == 0) out[0] = ((s[0] + s[1]) + (s[2] + s[3])) * (1.0f / (float)B_);
}

extern "C" void kernel_launch(void* const* d_in, const int* in_sizes, int n_in,
                              void* d_out, int out_size, void* d_ws, size_t ws_size,
                              hipStream_t stream) {
  const float* em  = (const float*)d_in[0];   // [B,T,K2] f32
  const float* tr  = (const float*)d_in[1];   // [K2,K2]  f32
  const int*   len = (const int*)d_in[2];     // [B] i32
  const int*   lab = (const int*)d_in[3];     // [B,T] i32
  float* out = (float*)d_out;
  float* ws  = (float*)d_ws;                  // 256 floats of per-batch scores

  crf_fwd_kernel<<<B_, 64, 0, stream>>>(em, tr, len, lab, ws);
  reduce_mean_kernel<<<1, 256, 0, stream>>>(ws, out);
}

// Round 7
// 426.206 us; speedup vs baseline: 1.3249x; 1.3249x over previous
//
#include <hip/hip_runtime.h>

// CRF NLL forward loss. B=256, T=2048, K2=52 (50 labels + START=50 + STOP=51).
// BIDIRECTIONAL linear-domain recurrence: score = s^T D_L M ... D_1 M v0 split at
// h = L/2. Wave 0 (forward):  v <- E_t * (M v),      t = 0..h-1
// Wave 1 (backward): u <- M^T (E_t * u),             t = L-1..h
// score = ln2*(C_f + C_b + log2(sum u.*v)).  Halves the sequential chain: the
// per-step cost (~450 cyc, allocator-bound per R4-R6) is fixed; steps 2048->1024.
// Renorm by a fixed always-positive lane every 4 steps (growth < 2^84 < fp32 max).

#define B_    256
#define T_    2048
#define K2_   52
#define LOG2E_ 1.4426950408889634f
#define LN2_   0.6931471805599453f

__device__ __forceinline__ float rdlane(float v, int src) {
  return __uint_as_float(__builtin_amdgcn_readlane(__float_as_uint(v), src));
}
__device__ __forceinline__ int imin(int a, int b) { return a < b ? a : b; }
__device__ __forceinline__ int imax(int a, int b) { return a > b ? a : b; }

// F(i, c): i = prev-state index, c = accumulator chain (i % 4)
#define FORALL52(F) \
  F(0,0) F(1,1) F(2,2) F(3,3) F(4,0) F(5,1) F(6,2) F(7,3) \
  F(8,0) F(9,1) F(10,2) F(11,3) F(12,0) F(13,1) F(14,2) F(15,3) \
  F(16,0) F(17,1) F(18,2) F(19,3) F(20,0) F(21,1) F(22,2) F(23,3) \
  F(24,0) F(25,1) F(26,2) F(27,3) F(28,0) F(29,1) F(30,2) F(31,3) \
  F(32,0) F(33,1) F(34,2) F(35,3) F(36,0) F(37,1) F(38,2) F(39,3) \
  F(40,0) F(41,1) F(42,2) F(43,3) F(48,0) F(49,1) F(50,2) F(51,3) \
  F(44,0) F(45,1) F(46,2) F(47,3)

// DECLM reads via IDX(i): forward IDX = n*K2+i (row), backward IDX = i*K2+n (col)
#define DECLM_F(i, c) float M_##i = __builtin_amdgcn_exp2f(tr[n * K2_ + i] * LOG2E_);
#define DECLM_B(i, c) float M_##i = __builtin_amdgcn_exp2f(tr[i * K2_ + n] * LOG2E_);
#define ACCF(i, c)  _a##c = fmaf(M_##i, rdlane(_src, i), _a##c);

#define MATVEC(OUTY) \
    float _a0 = 0.0f, _a1 = 0.0f, _a2 = 0.0f, _a3 = 0.0f; \
    FORALL52(ACCF) \
    float OUTY = (_a0 + _a1) + (_a2 + _a3);

// ---- forward steps: v' = E * (M v); renorm lane 50 (START, >0 always) ----
#define FSTEP_R(EV, NEWIDX) do {                                \
    float _ne  = emb[(NEWIDX) * K2_ + n];                       \
    float _m   = rdlane(vv, 50);                                \
    float _inv = __builtin_amdgcn_rcpf(_m);                     \
    C += __builtin_amdgcn_logf(_m);                             \
    float _E = __builtin_amdgcn_exp2f((EV) * LOG2E_);           \
    float _src = vv;                                            \
    MATVEC(_y)                                                  \
    vv = _y * _inv * _E;                                        \
    EV = _ne;                                                   \
  } while (0)
#define FSTEP_N(EV, NEWIDX) do {                                \
    float _ne  = emb[(NEWIDX) * K2_ + n];                       \
    float _E = __builtin_amdgcn_exp2f((EV) * LOG2E_);           \
    float _src = vv;                                            \
    MATVEC(_y)                                                  \
    vv = _y * _E;                                               \
    EV = _ne;                                                   \
  } while (0)

// ---- backward steps: u' = M^T (E * u); renorm lane 0 (all entries >0) ----
#define BSTEP_R(EV, NEWIDX) do {                                \
    float _ne  = emb[(NEWIDX) * K2_ + n];                       \
    float _m   = rdlane(vv, 0);                                 \
    float _inv = __builtin_amdgcn_rcpf(_m);                     \
    C += __builtin_amdgcn_logf(_m);                             \
    float _E = __builtin_amdgcn_exp2f((EV) * LOG2E_);           \
    float _src = vv * _E;                                       \
    MATVEC(_y)                                                  \
    vv = _y * _inv;                                             \
    EV = _ne;                                                   \
  } while (0)
#define BSTEP_N(EV, NEWIDX) do {                                \
    float _ne  = emb[(NEWIDX) * K2_ + n];                       \
    float _E = __builtin_amdgcn_exp2f((EV) * LOG2E_);           \
    float _src = vv * _E;                                       \
    MATVEC(_y)                                                  \
    vv = _y;                                                    \
    EV = _ne;                                                   \
  } while (0)

#define PIN(a,b,c,d,e,f,g,h,i,j,k,l,m) \
  asm volatile("" : "+v"(M_##a), "+v"(M_##b), "+v"(M_##c), "+v"(M_##d), \
                    "+v"(M_##e), "+v"(M_##f), "+v"(M_##g), "+v"(M_##h), \
                    "+v"(M_##i), "+v"(M_##j), "+v"(M_##k), "+v"(M_##l), \
                    "+v"(M_##m));
#define PIN_ALL \
  PIN( 0, 1, 2, 3, 4, 5, 6, 7, 8, 9,10,11,12) \
  PIN(13,14,15,16,17,18,19,20,21,22,23,24,25) \
  PIN(26,27,28,29,30,31,32,33,34,35,36,37,38) \
  PIN(39,40,41,42,43,44,45,46,47,48,49,50,51)

__launch_bounds__(128, 1)
__global__ void crf_fwd_kernel(const float* __restrict__ em,
                               const float* __restrict__ tr,
                               const int*  __restrict__ len,
                               const int*  __restrict__ lab,
                               float* __restrict__ per_b)
{
  const int b    = blockIdx.x;
  const int tid  = threadIdx.x;                      // 128 = 2 waves
  const int wave = tid >> 6;
  const int lane = tid & 63;
  const int n    = (lane < K2_) ? lane : (K2_ - 1);  // lanes 52..63 mirror lane 51
  const int L    = len[b];
  const int h    = L >> 1;                           // forward steps; backward L-h
  const float* emb = em + (size_t)b * (T_ * K2_);

  __shared__ float sU[64];     // backward wave's final u
  __shared__ float sCb[1];     // backward wave's log-offset
  __shared__ float sG[2];      // per-wave gold partials

  float vv, C = 0.0f;

  if (wave == 0) {
    // ---------------- forward half: h steps, rows 0..h-1 ----------------
    FORALL52(DECLM_F)
    PIN_ALL
    vv = (lane == 50) ? 1.0f : 0.0f;
    float e0 = emb[0 * K2_ + n];
    float e1 = emb[1 * K2_ + n];
    float e2 = emb[2 * K2_ + n];
    float e3 = emb[3 * K2_ + n];
    int t = 0;
    for (; t + 4 <= h; t += 4) {
      int i4 = imin(t + 4, T_ - 1), i5 = imin(t + 5, T_ - 1);
      int i6 = imin(t + 6, T_ - 1), i7 = imin(t + 7, T_ - 1);
      FSTEP_R(e0, i4);
      FSTEP_N(e1, i5);
      FSTEP_N(e2, i6);
      FSTEP_N(e3, i7);
    }
    int rem = h - t;
    if (rem > 0) FSTEP_R(e0, T_ - 1);
    if (rem > 1) FSTEP_N(e1, T_ - 1);
    if (rem > 2) FSTEP_N(e2, T_ - 1);
  } else {
    // ---------------- backward half: L-h steps, rows L-1 down to h ------
    FORALL52(DECLM_B)
    PIN_ALL
    vv = __builtin_amdgcn_exp2f(tr[(K2_ - 1) * K2_ + n] * LOG2E_);  // u_L = s
    int cnt = L - h;
    float e0 = emb[(L - 1) * K2_ + n];
    float e1 = emb[imax(L - 2, 0) * K2_ + n];
    float e2 = emb[imax(L - 3, 0) * K2_ + n];
    float e3 = emb[imax(L - 4, 0) * K2_ + n];
    int s = 0;
    for (; s + 4 <= cnt; s += 4) {
      int j4 = imax(L - 5 - s, 0), j5 = imax(L - 6 - s, 0);
      int j6 = imax(L - 7 - s, 0), j7 = imax(L - 8 - s, 0);
      BSTEP_R(e0, j4);
      BSTEP_N(e1, j5);
      BSTEP_N(e2, j6);
      BSTEP_N(e3, j7);
    }
    int rem = cnt - s;
    if (rem > 0) BSTEP_R(e0, 0);
    if (rem > 1) BSTEP_N(e1, 0);
    if (rem > 2) BSTEP_N(e2, 0);

    sU[lane] = vv;
    if (lane == 0) sCb[0] = C;
  }

  // ---- gold score (both waves, stride 128) ----
  float gold = 0.0f;
  const int* labb = lab + b * T_;
  for (int tt = tid; tt < L; tt += 128) {
    int l1 = labb[tt];
    int l0 = (tt == 0) ? 50 : labb[tt - 1];
    gold += emb[tt * K2_ + l1] + tr[l1 * K2_ + l0];
  }
  if (tid == 0) gold += tr[(K2_ - 1) * K2_ + labb[L - 1]];  // STOP <- last label
#pragma unroll
  for (int off = 32; off >= 1; off >>= 1)
    gold += __shfl_xor(gold, off, 64);
  if (lane == 0) sG[wave] = gold;

  __syncthreads();

  if (wave == 0) {
    // dot(u, v) + combine log-offsets
    float x = (lane < K2_) ? vv * sU[lane] : 0.0f;
#pragma unroll
    for (int off = 32; off >= 1; off >>= 1)
      x += __shfl_xor(x, off, 64);
    float fwd = (C + sCb[0] + __builtin_amdgcn_logf(x)) * LN2_;
    if (lane == 0) per_b[b] = fwd - (sG[0] + sG[1]);
  }
}

__global__ void reduce_mean_kernel(const float* __restrict__ per_b,
                                   float* __restrict__ out)
{
  const int tid = threadIdx.x;  // 256
  float v = per_b[tid];
#pragma unroll
  for (int off = 32; off >= 1; off >>= 1) v += __shfl_xor(v, off, 64);
  __shared__ float s[4];
  if ((tid & 63) == 0) s[tid >> 6] = v;
  __syncthreads();
  if (tid == 0) out[0] = ((s[0] + s[1]) + (s[2] + s[3])) * (1.0f / (float)B_);
}

extern "C" void kernel_launch(void* const* d_in, const int* in_sizes, int n_in,
                              void* d_out, int out_size, void* d_ws, size_t ws_size,
                              hipStream_t stream) {
  const float* em  = (const float*)d_in[0];   // [B,T,K2] f32
  const float* tr  = (const float*)d_in[1];   // [K2,K2]  f32
  const int*   len = (const int*)d_in[2];     // [B] i32
  const int*   lab = (const int*)d_in[3];     // [B,T] i32
  float* out = (float*)d_out;
  float* ws  = (float*)d_ws;                  // 256 floats of per-batch scores

  crf_fwd_kernel<<<B_, 128, 0, stream>>>(em, tr, len, lab, ws);
  reduce_mean_kernel<<<1, 256, 0, stream>>>(ws, out);
}